// Round 1
// baseline (274.693 us; speedup 1.0000x reference)
//
#include <hip/hip_runtime.h>
#include <math.h>

#define DIM    2048
#define B_     64
#define HQ     16
#define HK     4
#define G_     4
#define D_     128
#define SPAST  4095
#define SEQ    4096
#define NSPLIT 8
#define KSPLIT 4
#define EPS    1e-5f

// ---------------------------------------------------------------------------
// Split-K GEMM: part[ks][64][N] = A[64 x 2048] @ W[N x 2048]^T  (K chunk per ks)
// W selected per 64-col tile so one kernel serves fused QKV (Wq|Wk|Wv) and Wo.
// ---------------------------------------------------------------------------
__global__ __launch_bounds__(256) void gemm64_kernel(
    const float* __restrict__ A,
    const float* __restrict__ W0, const float* __restrict__ W1,
    const float* __restrict__ W2,
    float* __restrict__ part, int N)
{
    const int K  = 2048;
    const int KS = K / KSPLIT;
    int n0 = blockIdx.x * 64;
    int ks = blockIdx.y;
    const float* W; int wc;
    if (n0 < 2048)      { W = W0; wc = n0; }
    else if (n0 < 2560) { W = W1; wc = n0 - 2048; }
    else                { W = W2; wc = n0 - 2560; }

    __shared__ float xt[64][69];   // xt[k][b], pad 69 -> conflict-free
    __shared__ float wt[64][69];   // wt[k][c]

    int t  = threadIdx.x;
    int tx = t & 15, ty = t >> 4;  // tx -> 4 cols, ty -> 4 rows
    float acc[4][4] = {};

    int k0 = ks * KS;
    for (int kc = k0; kc < k0 + KS; kc += 64) {
        __syncthreads();
        #pragma unroll
        for (int r = 0; r < 4; ++r) {
            int bi = ty + r * 16;
            float4 xv = *(const float4*)&A[(size_t)bi * K + kc + tx * 4];
            xt[tx*4+0][bi] = xv.x; xt[tx*4+1][bi] = xv.y;
            xt[tx*4+2][bi] = xv.z; xt[tx*4+3][bi] = xv.w;
            float4 wv = *(const float4*)&W[(size_t)(wc + bi) * K + kc + tx * 4];
            wt[tx*4+0][bi] = wv.x; wt[tx*4+1][bi] = wv.y;
            wt[tx*4+2][bi] = wv.z; wt[tx*4+3][bi] = wv.w;
        }
        __syncthreads();
        #pragma unroll 8
        for (int k = 0; k < 64; ++k) {
            float xr[4], wr[4];
            #pragma unroll
            for (int i = 0; i < 4; ++i) xr[i] = xt[k][ty*4+i];
            #pragma unroll
            for (int j = 0; j < 4; ++j) wr[j] = wt[k][tx*4+j];
            #pragma unroll
            for (int i = 0; i < 4; ++i)
                #pragma unroll
                for (int j = 0; j < 4; ++j)
                    acc[i][j] += xr[i] * wr[j];
        }
    }
    #pragma unroll
    for (int i = 0; i < 4; ++i)
        #pragma unroll
        for (int j = 0; j < 4; ++j)
            part[((size_t)ks * 64 + ty*4+i) * N + n0 + tx*4 + j] = acc[i][j];
}

// ---------------------------------------------------------------------------
// Fuse split-K reduce + per-head RMSNorm + RoPE. One wave per (b, head) row.
// Rows: h<16 -> q head h ; 16..19 -> k head ; 20..23 -> v head (copy only).
// Lane l handles elements l and l+64 (the RoPE rotation pair).
// ---------------------------------------------------------------------------
__global__ __launch_bounds__(256) void rope_norm_kernel(
    const float* __restrict__ part1, const int* __restrict__ pos,
    const float* __restrict__ qn_w, const float* __restrict__ kn_w,
    float* __restrict__ qr, float* __restrict__ kr, float* __restrict__ vr)
{
    int row  = blockIdx.x * 4 + (threadIdx.x >> 6);
    int lane = threadIdx.x & 63;
    int b = row / 24, h = row % 24;
    int col, type;
    if (h < 16)      { type = 0; col = h * 128; }
    else if (h < 20) { type = 1; col = 2048 + (h - 16) * 128; }
    else             { type = 2; col = 2560 + (h - 20) * 128; }

    float t1 = 0.f, t2 = 0.f;
    #pragma unroll
    for (int ksp = 0; ksp < KSPLIT; ++ksp) {
        t1 += part1[((size_t)ksp * 64 + b) * 3072 + col + lane];
        t2 += part1[((size_t)ksp * 64 + b) * 3072 + col + lane + 64];
    }

    if (type == 2) {   // v: no norm, no rope (branch is wave-uniform)
        vr[(b * HK + (h - 20)) * 128 + lane]      = t1;
        vr[(b * HK + (h - 20)) * 128 + lane + 64] = t2;
        return;
    }

    float ss = t1 * t1 + t2 * t2;
    ss += __shfl_xor(ss, 1);  ss += __shfl_xor(ss, 2);  ss += __shfl_xor(ss, 4);
    ss += __shfl_xor(ss, 8);  ss += __shfl_xor(ss, 16); ss += __shfl_xor(ss, 32);
    float rn = 1.0f / sqrtf(ss * (1.0f / 128.0f) + EPS);
    const float* wn = (type == 0) ? qn_w : kn_w;
    float n1 = t1 * rn * wn[lane];
    float n2 = t2 * rn * wn[lane + 64];

    // inv_freq = 10000^(-2l/128); freqs = pos * inv_freq (fp32, same as ref)
    float invf = powf(10000.0f, -(float)lane * (1.0f / 64.0f));
    float f    = (float)pos[b] * invf;
    float sv = sinf(f), cv = cosf(f);
    float o1 = n1 * cv - n2 * sv;
    float o2 = n2 * cv + n1 * sv;

    if (type == 0) {
        qr[(b * HQ + h) * 128 + lane]      = o1;
        qr[(b * HQ + h) * 128 + lane + 64] = o2;
    } else {
        kr[(b * HK + (h - 16)) * 128 + lane]      = o1;
        kr[(b * HK + (h - 16)) * 128 + lane + 64] = o2;
    }
}

// ---------------------------------------------------------------------------
// Flash-decode attention (scale = 1.0). Grid: B*HK*NSPLIT blocks, 4 waves.
// Each half-wave (32 lanes x float4) owns one KV position per iteration.
// Online softmax per q-head (G_=4 heads per kv head). Partials to ws.
// ---------------------------------------------------------------------------
__global__ __launch_bounds__(256) void attn_kernel(
    const float* __restrict__ kc, const float* __restrict__ vc,
    const float* __restrict__ qr, const float* __restrict__ kr,
    const float* __restrict__ vr,
    float* __restrict__ pacc, float* __restrict__ pml)
{
    int blk  = blockIdx.x;
    int sp   = blk & (NSPLIT - 1);
    int hk   = (blk / NSPLIT) & (HK - 1);
    int b    = blk / (NSPLIT * HK);
    int t    = threadIdx.x;
    int w    = t >> 6;
    int lane = t & 63;
    int half = (lane >> 5) & 1;
    int l32  = lane & 31;

    float4 q4[G_];
    #pragma unroll
    for (int g = 0; g < G_; ++g)
        q4[g] = *(const float4*)&qr[(size_t)(b * HQ + hk * G_ + g) * D_ + l32 * 4];

    const float* kbase = kc + (size_t)(b * HK + hk) * SPAST * D_;
    const float* vbase = vc + (size_t)(b * HK + hk) * SPAST * D_;
    const float* knew  = kr + (b * HK + hk) * D_;
    const float* vnew  = vr + (b * HK + hk) * D_;

    float  m[G_], lsum[G_];
    float4 acc[G_];
    #pragma unroll
    for (int g = 0; g < G_; ++g) {
        m[g] = -1e30f; lsum[g] = 0.f; acc[g] = make_float4(0.f, 0.f, 0.f, 0.f);
    }

    int s0 = sp * (SEQ / NSPLIT);

    int s = s0 + w * 2 + half;   // iteration 0 position for this half-wave
    const float* kp = (s < SPAST) ? (kbase + (size_t)s * D_) : knew;
    const float* vp = (s < SPAST) ? (vbase + (size_t)s * D_) : vnew;
    float4 k4 = *(const float4*)(kp + l32 * 4);
    float4 v4 = *(const float4*)(vp + l32 * 4);

    for (int i = 0; i < 64; ++i) {
        float4 k4n, v4n;
        if (i < 63) {   // register prefetch of next pair
            int sn = s0 + ((i + 1) * 4 + w) * 2 + half;
            const float* kpn = (sn < SPAST) ? (kbase + (size_t)sn * D_) : knew;
            const float* vpn = (sn < SPAST) ? (vbase + (size_t)sn * D_) : vnew;
            k4n = *(const float4*)(kpn + l32 * 4);
            v4n = *(const float4*)(vpn + l32 * 4);
        }
        #pragma unroll
        for (int g = 0; g < G_; ++g) {
            float p = q4[g].x * k4.x + q4[g].y * k4.y
                    + q4[g].z * k4.z + q4[g].w * k4.w;
            p += __shfl_xor(p, 1);
            p += __shfl_xor(p, 2);
            p += __shfl_xor(p, 4);
            p += __shfl_xor(p, 8);
            p += __shfl_xor(p, 16);
            // branch condition is uniform across the 32-lane half
            if (p <= m[g]) {
                float e = __expf(p - m[g]);
                lsum[g] += e;
                acc[g].x += e * v4.x; acc[g].y += e * v4.y;
                acc[g].z += e * v4.z; acc[g].w += e * v4.w;
            } else {
                float al = __expf(m[g] - p);
                m[g] = p;
                lsum[g] = lsum[g] * al + 1.0f;
                acc[g].x = acc[g].x * al + v4.x;
                acc[g].y = acc[g].y * al + v4.y;
                acc[g].z = acc[g].z * al + v4.z;
                acc[g].w = acc[g].w * al + v4.w;
            }
        }
        if (i < 63) { k4 = k4n; v4 = v4n; }
    }

    // merge 8 (wave, half) partials within the block via LDS
    __shared__ float s_acc[4][2][G_][D_];
    __shared__ float s_m[4][2][G_];
    __shared__ float s_l[4][2][G_];
    #pragma unroll
    for (int g = 0; g < G_; ++g) {
        s_acc[w][half][g][l32*4+0] = acc[g].x;
        s_acc[w][half][g][l32*4+1] = acc[g].y;
        s_acc[w][half][g][l32*4+2] = acc[g].z;
        s_acc[w][half][g][l32*4+3] = acc[g].w;
        if (l32 == 0) { s_m[w][half][g] = m[g]; s_l[w][half][g] = lsum[g]; }
    }
    __syncthreads();

    if (t < 128) {
        int d = t;
        #pragma unroll
        for (int g = 0; g < G_; ++g) {
            float M = -1e30f;
            #pragma unroll
            for (int j = 0; j < 8; ++j) M = fmaxf(M, s_m[j >> 1][j & 1][g]);
            float L = 0.f, a = 0.f;
            #pragma unroll
            for (int j = 0; j < 8; ++j) {
                float e = __expf(s_m[j >> 1][j & 1][g] - M);
                L += e * s_l[j >> 1][j & 1][g];
                a += e * s_acc[j >> 1][j & 1][g][d];
            }
            int hq = hk * G_ + g;
            size_t pidx = (size_t)(b * HQ + hq) * NSPLIT + sp;
            pacc[pidx * D_ + d] = a;
            if (d == 0) { pml[pidx * 2 + 0] = M; pml[pidx * 2 + 1] = L; }
        }
    }
}

// ---------------------------------------------------------------------------
// Merge NSPLIT partials per (b, hq); write attn row [b][hq*128+d].
// ---------------------------------------------------------------------------
__global__ void attn_combine_kernel(const float* __restrict__ pacc,
                                    const float* __restrict__ pml,
                                    float* __restrict__ attnb)
{
    int bh = blockIdx.x;     // b*HQ + hq
    int d  = threadIdx.x;    // 0..127
    float M = -1e30f;
    #pragma unroll
    for (int s = 0; s < NSPLIT; ++s)
        M = fmaxf(M, pml[(size_t)(bh * NSPLIT + s) * 2]);
    float L = 0.f, a = 0.f;
    #pragma unroll
    for (int s = 0; s < NSPLIT; ++s) {
        float e = __expf(pml[(size_t)(bh * NSPLIT + s) * 2] - M);
        L += e * pml[(size_t)(bh * NSPLIT + s) * 2 + 1];
        a += e * pacc[(size_t)(bh * NSPLIT + s) * D_ + d];
    }
    attnb[(size_t)bh * D_ + d] = a / L;
}

// ---------------------------------------------------------------------------
// Sum the KSPLIT partials of the output projection into d_out.
// ---------------------------------------------------------------------------
__global__ void sum_parts_kernel(const float* __restrict__ part,
                                 float* __restrict__ out)
{
    int i = blockIdx.x * 256 + threadIdx.x;
    float v = 0.f;
    #pragma unroll
    for (int ksp = 0; ksp < KSPLIT; ++ksp)
        v += part[(size_t)ksp * B_ * DIM + i];
    out[i] = v;
}

// ---------------------------------------------------------------------------
extern "C" void kernel_launch(void* const* d_in, const int* in_sizes, int n_in,
                              void* d_out, int out_size, void* d_ws, size_t ws_size,
                              hipStream_t stream)
{
    const float* x   = (const float*)d_in[0];
    const int*   pos = (const int*)  d_in[1];
    const float* kc  = (const float*)d_in[2];
    const float* vc  = (const float*)d_in[3];
    const float* Wq  = (const float*)d_in[4];
    const float* Wk  = (const float*)d_in[5];
    const float* Wv  = (const float*)d_in[6];
    const float* Wo  = (const float*)d_in[7];
    const float* qn  = (const float*)d_in[8];
    const float* kn  = (const float*)d_in[9];

    float* ws    = (float*)d_ws;
    float* part1 = ws;                                       // KSPLIT*64*3072
    float* qr    = part1 + (size_t)KSPLIT * 64 * 3072;       // 64*16*128
    float* kr    = qr    + (size_t)64 * HQ * D_;             // 64*4*128
    float* vr    = kr    + (size_t)64 * HK * D_;             // 64*4*128
    float* pacc  = vr    + (size_t)64 * HK * D_;             // 64*16*8*128
    float* pml   = pacc  + (size_t)64 * HQ * NSPLIT * D_;    // 64*16*8*2
    float* attnb = pml   + (size_t)64 * HQ * NSPLIT * 2;     // 64*2048
    float* part4 = attnb + (size_t)64 * DIM;                 // KSPLIT*64*2048

    // 1) fused QKV projection (split-K partials)
    gemm64_kernel<<<dim3(48, KSPLIT), 256, 0, stream>>>(x, Wq, Wk, Wv, part1, 3072);
    // 2) split-K reduce + RMSNorm + RoPE
    rope_norm_kernel<<<384, 256, 0, stream>>>(part1, pos, qn, kn, qr, kr, vr);
    // 3) flash-decode attention over 4096 positions (incl. appended token)
    attn_kernel<<<B_ * HK * NSPLIT, 256, 0, stream>>>(kc, vc, qr, kr, vr, pacc, pml);
    // 4) merge splits
    attn_combine_kernel<<<B_ * HQ, 128, 0, stream>>>(pacc, pml, attnb);
    // 5) output projection (split-K partials)
    gemm64_kernel<<<dim3(32, KSPLIT), 256, 0, stream>>>(attnb, Wo, Wo, Wo, part4, 2048);
    // 6) reduce partials into d_out
    sum_parts_kernel<<<(B_ * DIM) / 256, 256, 0, stream>>>(part4, (float*)d_out);
}

// Round 2
// 261.135 us; speedup vs baseline: 1.0519x; 1.0519x over previous
//
#include <hip/hip_runtime.h>
#include <math.h>

#define DIM    2048
#define B_     64
#define HQ     16
#define HK     4
#define G_     4
#define D_     128
#define SPAST  4095
#define SEQ    4096
#define NSPLIT 8
#define KSPLIT 4
#define EPS    1e-5f

// ---------------------------------------------------------------------------
// Split-K GEMM: part[ks][64][N] = A[64 x 2048] @ W[N x 2048]^T  (K chunk per ks)
// ---------------------------------------------------------------------------
__global__ __launch_bounds__(256) void gemm64_kernel(
    const float* __restrict__ A,
    const float* __restrict__ W0, const float* __restrict__ W1,
    const float* __restrict__ W2,
    float* __restrict__ part, int N)
{
    const int K  = 2048;
    const int KS = K / KSPLIT;
    int n0 = blockIdx.x * 64;
    int ks = blockIdx.y;
    const float* W; int wc;
    if (n0 < 2048)      { W = W0; wc = n0; }
    else if (n0 < 2560) { W = W1; wc = n0 - 2048; }
    else                { W = W2; wc = n0 - 2560; }

    __shared__ float xt[64][69];
    __shared__ float wt[64][69];

    int t  = threadIdx.x;
    int tx = t & 15, ty = t >> 4;
    float acc[4][4] = {};

    int k0 = ks * KS;
    for (int kc = k0; kc < k0 + KS; kc += 64) {
        __syncthreads();
        #pragma unroll
        for (int r = 0; r < 4; ++r) {
            int bi = ty + r * 16;
            float4 xv = *(const float4*)&A[(size_t)bi * K + kc + tx * 4];
            xt[tx*4+0][bi] = xv.x; xt[tx*4+1][bi] = xv.y;
            xt[tx*4+2][bi] = xv.z; xt[tx*4+3][bi] = xv.w;
            float4 wv = *(const float4*)&W[(size_t)(wc + bi) * K + kc + tx * 4];
            wt[tx*4+0][bi] = wv.x; wt[tx*4+1][bi] = wv.y;
            wt[tx*4+2][bi] = wv.z; wt[tx*4+3][bi] = wv.w;
        }
        __syncthreads();
        #pragma unroll 8
        for (int k = 0; k < 64; ++k) {
            float xr[4], wr[4];
            #pragma unroll
            for (int i = 0; i < 4; ++i) xr[i] = xt[k][ty*4+i];
            #pragma unroll
            for (int j = 0; j < 4; ++j) wr[j] = wt[k][tx*4+j];
            #pragma unroll
            for (int i = 0; i < 4; ++i)
                #pragma unroll
                for (int j = 0; j < 4; ++j)
                    acc[i][j] += xr[i] * wr[j];
        }
    }
    #pragma unroll
    for (int i = 0; i < 4; ++i)
        #pragma unroll
        for (int j = 0; j < 4; ++j)
            part[((size_t)ks * 64 + ty*4+i) * N + n0 + tx*4 + j] = acc[i][j];
}

// ---------------------------------------------------------------------------
// Split-K reduce + per-head RMSNorm + RoPE.
// ---------------------------------------------------------------------------
__global__ __launch_bounds__(256) void rope_norm_kernel(
    const float* __restrict__ part1, const int* __restrict__ pos,
    const float* __restrict__ qn_w, const float* __restrict__ kn_w,
    float* __restrict__ qr, float* __restrict__ kr, float* __restrict__ vr)
{
    int row  = blockIdx.x * 4 + (threadIdx.x >> 6);
    int lane = threadIdx.x & 63;
    int b = row / 24, h = row % 24;
    int col, type;
    if (h < 16)      { type = 0; col = h * 128; }
    else if (h < 20) { type = 1; col = 2048 + (h - 16) * 128; }
    else             { type = 2; col = 2560 + (h - 20) * 128; }

    float t1 = 0.f, t2 = 0.f;
    #pragma unroll
    for (int ksp = 0; ksp < KSPLIT; ++ksp) {
        t1 += part1[((size_t)ksp * 64 + b) * 3072 + col + lane];
        t2 += part1[((size_t)ksp * 64 + b) * 3072 + col + lane + 64];
    }

    if (type == 2) {
        vr[(b * HK + (h - 20)) * 128 + lane]      = t1;
        vr[(b * HK + (h - 20)) * 128 + lane + 64] = t2;
        return;
    }

    float ss = t1 * t1 + t2 * t2;
    ss += __shfl_xor(ss, 1);  ss += __shfl_xor(ss, 2);  ss += __shfl_xor(ss, 4);
    ss += __shfl_xor(ss, 8);  ss += __shfl_xor(ss, 16); ss += __shfl_xor(ss, 32);
    float rn = 1.0f / sqrtf(ss * (1.0f / 128.0f) + EPS);
    const float* wn = (type == 0) ? qn_w : kn_w;
    float n1 = t1 * rn * wn[lane];
    float n2 = t2 * rn * wn[lane + 64];

    float invf = powf(10000.0f, -(float)lane * (1.0f / 64.0f));
    float f    = (float)pos[b] * invf;
    float sv = sinf(f), cv = cosf(f);
    float o1 = n1 * cv - n2 * sv;
    float o2 = n2 * cv + n1 * sv;

    if (type == 0) {
        qr[(b * HQ + h) * 128 + lane]      = o1;
        qr[(b * HQ + h) * 128 + lane + 64] = o2;
    } else {
        kr[(b * HK + (h - 16)) * 128 + lane]      = o1;
        kr[(b * HK + (h - 16)) * 128 + lane + 64] = o2;
    }
}

// ---------------------------------------------------------------------------
// Flash-decode attention (scale = 1.0). Grid: B*HK*NSPLIT blocks, 4 waves.
// Each half-wave (32 lanes x float4) owns one KV position per iteration.
//
// Score: each lane computes 4 partial dots (one per q-head of this kv group)
// over d = l32*4..+3, then a transposed butterfly (7 shfls total for all 4
// heads) leaves lane l holding the FULL score for head g = l&3.
// PV: lane l accumulates head (l&3) over d-chunk (l32>>2)*16..+15 (16 floats),
// with defer-max online softmax (rescale only when p > m+8) -> 1 exp/pos/lane.
// ---------------------------------------------------------------------------
__global__ __launch_bounds__(256) void attn_kernel(
    const float* __restrict__ kc, const float* __restrict__ vc,
    const float* __restrict__ qr, const float* __restrict__ kr,
    const float* __restrict__ vr,
    float* __restrict__ pacc, float* __restrict__ pml)
{
    int blk  = blockIdx.x;
    int sp   = blk & (NSPLIT - 1);
    int hk   = (blk / NSPLIT) & (HK - 1);
    int b    = blk / (NSPLIT * HK);
    int t    = threadIdx.x;
    int w    = t >> 6;
    int lane = t & 63;
    int half = (lane >> 5) & 1;
    int l32  = lane & 31;
    int g    = lane & 3;          // this lane's owned head (within kv group)
    int dbase = (l32 >> 2) * 16;  // this lane's owned d-chunk (16 floats)

    float4 q4[G_];
    #pragma unroll
    for (int gg = 0; gg < G_; ++gg)
        q4[gg] = *(const float4*)&qr[(size_t)(b * HQ + hk * G_ + gg) * D_ + l32 * 4];

    const float* kbase = kc + (size_t)(b * HK + hk) * SPAST * D_;
    const float* vbase = vc + (size_t)(b * HK + hk) * SPAST * D_;
    const float* knew  = kr + (b * HK + hk) * D_;
    const float* vnew  = vr + (b * HK + hk) * D_;

    float  m = -1e30f, lsum = 0.f;
    float4 acc[4];
    #pragma unroll
    for (int j = 0; j < 4; ++j) acc[j] = make_float4(0.f, 0.f, 0.f, 0.f);

    int s0 = sp * (SEQ / NSPLIT);
    int s  = s0 + w * 2 + half;
    const float* kp = (s < SPAST) ? (kbase + (size_t)s * D_) : knew;
    float4 k4 = *(const float4*)(kp + l32 * 4);

    int sel1 = lane & 1, sel2 = lane & 2;

    for (int i = 0; i < 64; ++i) {
        // V row for the CURRENT position (issued early; consumed after reduce)
        const float* vp = (s < SPAST) ? (vbase + (size_t)s * D_) : vnew;
        float4 v4[4];
        #pragma unroll
        for (int j = 0; j < 4; ++j)
            v4[j] = *(const float4*)(vp + dbase + j * 4);

        // K prefetch for next iteration
        float4 k4n;
        int sn = s;
        if (i < 63) {
            sn = s0 + ((i + 1) * 4 + w) * 2 + half;
            const float* kpn = (sn < SPAST) ? (kbase + (size_t)sn * D_) : knew;
            k4n = *(const float4*)(kpn + l32 * 4);
        }

        // 4 partial dots (this lane's d = l32*4..+3)
        float p0 = q4[0].x*k4.x + q4[0].y*k4.y + q4[0].z*k4.z + q4[0].w*k4.w;
        float p1 = q4[1].x*k4.x + q4[1].y*k4.y + q4[1].z*k4.z + q4[1].w*k4.w;
        float p2 = q4[2].x*k4.x + q4[2].y*k4.y + q4[2].z*k4.z + q4[2].w*k4.w;
        float p3 = q4[3].x*k4.x + q4[3].y*k4.y + q4[3].z*k4.z + q4[3].w*k4.w;

        // transposed butterfly: after this, lane holds full score of head lane&3
        float ka = sel1 ? p1 : p0, sa = sel1 ? p0 : p1;
        float kb = sel1 ? p3 : p2, sb = sel1 ? p2 : p3;
        float s01 = ka + __shfl_xor(sa, 1);
        float s23 = kb + __shfl_xor(sb, 1);
        float kc2 = sel2 ? s23 : s01, sc = sel2 ? s01 : s23;
        float p = kc2 + __shfl_xor(sc, 2);
        p += __shfl_xor(p, 4);
        p += __shfl_xor(p, 8);
        p += __shfl_xor(p, 16);

        // defer-max online softmax (rescale rare: p > m+8)
        if (p > m + 8.0f) {
            float al = __expf(m - p);
            m = p;
            lsum *= al;
            #pragma unroll
            for (int j = 0; j < 4; ++j) {
                acc[j].x *= al; acc[j].y *= al; acc[j].z *= al; acc[j].w *= al;
            }
        }
        float e = __expf(p - m);
        lsum += e;
        #pragma unroll
        for (int j = 0; j < 4; ++j) {
            acc[j].x += e * v4[j].x; acc[j].y += e * v4[j].y;
            acc[j].z += e * v4[j].z; acc[j].w += e * v4[j].w;
        }

        k4 = k4n; s = sn;
    }

    // merge 8 (wave, half) partials within the block via LDS
    __shared__ float s_acc[8][G_][D_];
    __shared__ float s_m[8][G_];
    __shared__ float s_l[8][G_];
    int wh = w * 2 + half;
    #pragma unroll
    for (int j = 0; j < 4; ++j)
        *(float4*)&s_acc[wh][g][dbase + j * 4] = acc[j];
    if (l32 < 4) { s_m[wh][l32] = m; s_l[wh][l32] = lsum; }  // l32==g for l32<4
    __syncthreads();

    if (t < 128) {
        int d = t;
        #pragma unroll
        for (int gg = 0; gg < G_; ++gg) {
            float M = -1e30f;
            #pragma unroll
            for (int j = 0; j < 8; ++j) M = fmaxf(M, s_m[j][gg]);
            float L = 0.f, a = 0.f;
            #pragma unroll
            for (int j = 0; j < 8; ++j) {
                float e = __expf(s_m[j][gg] - M);
                L += e * s_l[j][gg];
                a += e * s_acc[j][gg][d];
            }
            int hq = hk * G_ + gg;
            size_t pidx = (size_t)(b * HQ + hq) * NSPLIT + sp;
            pacc[pidx * D_ + d] = a;
            if (d == 0) { pml[pidx * 2 + 0] = M; pml[pidx * 2 + 1] = L; }
        }
    }
}

// ---------------------------------------------------------------------------
__global__ void attn_combine_kernel(const float* __restrict__ pacc,
                                    const float* __restrict__ pml,
                                    float* __restrict__ attnb)
{
    int bh = blockIdx.x;
    int d  = threadIdx.x;
    float M = -1e30f;
    #pragma unroll
    for (int s = 0; s < NSPLIT; ++s)
        M = fmaxf(M, pml[(size_t)(bh * NSPLIT + s) * 2]);
    float L = 0.f, a = 0.f;
    #pragma unroll
    for (int s = 0; s < NSPLIT; ++s) {
        float e = __expf(pml[(size_t)(bh * NSPLIT + s) * 2] - M);
        L += e * pml[(size_t)(bh * NSPLIT + s) * 2 + 1];
        a += e * pacc[(size_t)(bh * NSPLIT + s) * D_ + d];
    }
    attnb[(size_t)bh * D_ + d] = a / L;
}

// ---------------------------------------------------------------------------
__global__ void sum_parts_kernel(const float* __restrict__ part,
                                 float* __restrict__ out)
{
    int i = blockIdx.x * 256 + threadIdx.x;
    float v = 0.f;
    #pragma unroll
    for (int ksp = 0; ksp < KSPLIT; ++ksp)
        v += part[(size_t)ksp * B_ * DIM + i];
    out[i] = v;
}

// ---------------------------------------------------------------------------
extern "C" void kernel_launch(void* const* d_in, const int* in_sizes, int n_in,
                              void* d_out, int out_size, void* d_ws, size_t ws_size,
                              hipStream_t stream)
{
    const float* x   = (const float*)d_in[0];
    const int*   pos = (const int*)  d_in[1];
    const float* kc  = (const float*)d_in[2];
    const float* vc  = (const float*)d_in[3];
    const float* Wq  = (const float*)d_in[4];
    const float* Wk  = (const float*)d_in[5];
    const float* Wv  = (const float*)d_in[6];
    const float* Wo  = (const float*)d_in[7];
    const float* qn  = (const float*)d_in[8];
    const float* kn  = (const float*)d_in[9];

    float* ws    = (float*)d_ws;
    float* part1 = ws;
    float* qr    = part1 + (size_t)KSPLIT * 64 * 3072;
    float* kr    = qr    + (size_t)64 * HQ * D_;
    float* vr    = kr    + (size_t)64 * HK * D_;
    float* pacc  = vr    + (size_t)64 * HK * D_;
    float* pml   = pacc  + (size_t)64 * HQ * NSPLIT * D_;
    float* attnb = pml   + (size_t)64 * HQ * NSPLIT * 2;
    float* part4 = attnb + (size_t)64 * DIM;

    gemm64_kernel<<<dim3(48, KSPLIT), 256, 0, stream>>>(x, Wq, Wk, Wv, part1, 3072);
    rope_norm_kernel<<<384, 256, 0, stream>>>(part1, pos, qn, kn, qr, kr, vr);
    attn_kernel<<<B_ * HK * NSPLIT, 256, 0, stream>>>(kc, vc, qr, kr, vr, pacc, pml);
    attn_combine_kernel<<<B_ * HQ, 128, 0, stream>>>(pacc, pml, attnb);
    gemm64_kernel<<<dim3(32, KSPLIT), 256, 0, stream>>>(attnb, Wo, Wo, Wo, part4, 2048);
    sum_parts_kernel<<<(B_ * DIM) / 256, 256, 0, stream>>>(part4, (float*)d_out);
}